// Round 2
// baseline (41.842 us; speedup 1.0000x reference)
//
#include <hip/hip_runtime.h>

#define NPERS 64
#define NJOINT 15
#define NDEPTH 128
#define BIGF 100000.0f
#define EPSF 1e-8f

__global__ __launch_bounds__(128) void pose_match_kernel(
    const float* __restrict__ poses_3d,   // (B,NP,NJ,ND,3)
    const float* __restrict__ p2d,        // (B,NP,NJ,2)
    const float* __restrict__ vis,        // (B,NP,NJ)
    const int*   __restrict__ nper,       // (B,)
    const float* __restrict__ Rm,         // (B,3,3)
    const float* __restrict__ Tm,         // (B,3)
    const float* __restrict__ fm,         // (B,2)
    const float* __restrict__ cm,         // (B,2)
    const float* __restrict__ iw_,        // (B,)
    const float* __restrict__ ih_,        // (B,)
    float* __restrict__ out)              // (B,NP,NJ,ND)
{
    const int b = blockIdx.x / NPERS;
    const int p = blockIdx.x % NPERS;
    const int d = threadIdx.x;

    __shared__ float4 sq[NPERS][NJOINT];   // {vis, rx, ry, unused}
    __shared__ float sterm2[NPERS];
    __shared__ float sinv[NPERS];

    // ---- stage per-batch candidate data into LDS ----
    for (int i = threadIdx.x; i < NPERS * NJOINT; i += 128) {
        int q = i / NJOINT, j = i % NJOINT;
        float v  = vis[(b * NPERS + q) * NJOINT + j];
        float rx = p2d[((b * NPERS + q) * NJOINT + j) * 2 + 0];
        float ry = p2d[((b * NPERS + q) * NJOINT + j) * 2 + 1];
        sq[q][j] = make_float4(v, rx, ry, 0.0f);
    }
    __syncthreads();
    if (threadIdx.x < NPERS) {
        int q = threadIdx.x;
        float t2 = 0.0f, vs = 0.0f;
        #pragma unroll
        for (int j = 0; j < NJOINT; ++j) {
            float4 v = sq[q][j];
            t2 = fmaf(v.y * v.y + v.z * v.z, v.x, t2);
            vs += v.x;
        }
        sterm2[q] = t2;
        sinv[q]   = 1.0f / (vs + EPSF);
    }
    __syncthreads();

    // ---- camera params (wave-uniform) ----
    const float R00 = Rm[b*9+0], R01 = Rm[b*9+1], R02 = Rm[b*9+2];
    const float R10 = Rm[b*9+3], R11 = Rm[b*9+4], R12 = Rm[b*9+5];
    const float R20 = Rm[b*9+6], R21 = Rm[b*9+7], R22 = Rm[b*9+8];
    const float T0 = Tm[b*3+0], T1 = Tm[b*3+1], T2 = Tm[b*3+2];
    const float fx = fm[b*2+0], fy = fm[b*2+1];
    const float cx = cm[b*2+0], cy = cm[b*2+1];
    const float iwm1 = iw_[b] - 1.0f;
    const float ihm1 = ih_[b] - 1.0f;
    const int   npv  = nper[b];

    // ---- project this thread's 15 joints ----
    float X[NJOINT], Y[NJOINT], P2[NJOINT];
    #pragma unroll
    for (int j = 0; j < NJOINT; ++j) {
        int base = (((b * NPERS + p) * NJOINT + j) * NDEPTH + d) * 3;
        float a0 = poses_3d[base + 0] - T0;
        float a1 = poses_3d[base + 1] - T1;
        float a2 = poses_3d[base + 2] - T2;
        float xc0 = R00 * a0 + R01 * a1 + R02 * a2;
        float xc1 = R10 * a0 + R11 * a1 + R12 * a2;
        float xc2 = R20 * a0 + R21 * a1 + R22 * a2;
        float xx = fx * xc0 / xc2 + cx;
        float yy = fy * xc1 / xc2 + cy;
        X[j] = xx; Y[j] = yy;
        P2[j] = xx * xx + yy * yy;
    }

    // ---- argmin over candidates q (ascending, strict <, matches np.argmin) ----
    float bestv = 3.0e38f;
    int   bestq = 0;
    for (int q = 0; q < NPERS; ++q) {
        float s1 = 0.0f, s3 = 0.0f;
        #pragma unroll
        for (int j = 0; j < NJOINT; ++j) {
            float4 v = sq[q][j];
            s1 = fmaf(P2[j], v.x, s1);
            float t = X[j] * v.y;
            t = fmaf(Y[j], v.z, t);
            s3 = fmaf(v.x, t, s3);
        }
        float dist = (s1 + sterm2[q] - 2.0f * s3) * sinv[q];
        dist = (q < npv) ? dist : BIGF;
        if (dist < bestv) { bestv = dist; bestq = q; }
    }

    // ---- phase 2: score against matched candidate ----
    const int obase = ((b * NPERS + p) * NJOINT) * NDEPTH + d;
    #pragma unroll
    for (int j = 0; j < NJOINT; ++j) {
        float4 v = sq[bestq][j];
        float dx = X[j] - v.y;
        float dy = Y[j] - v.z;
        float md = fmaf(dx, dx, dy * dy);
        float sc = expf(-md * (1.0f / 225.0f));
        float inb = (X[j] >= 0.0f && Y[j] >= 0.0f &&
                     X[j] <= iwm1 && Y[j] <= ihm1) ? 1.0f : 0.0f;
        out[obase + j * NDEPTH] = sc * inb * v.x;
    }
}

extern "C" void kernel_launch(void* const* d_in, const int* in_sizes, int n_in,
                              void* d_out, int out_size, void* d_ws, size_t ws_size,
                              hipStream_t stream) {
    const float* poses_3d = (const float*)d_in[0];
    const float* p2d      = (const float*)d_in[1];
    const float* vis      = (const float*)d_in[2];
    const int*   nper     = (const int*)d_in[3];
    const float* Rm       = (const float*)d_in[4];
    const float* Tm       = (const float*)d_in[5];
    const float* fm       = (const float*)d_in[6];
    const float* cm       = (const float*)d_in[7];
    const float* iw       = (const float*)d_in[8];
    const float* ih       = (const float*)d_in[9];
    float* out = (float*)d_out;

    const int B = in_sizes[3];  // num_persons_ref has B elements
    dim3 grid(B * NPERS);
    dim3 block(128);
    pose_match_kernel<<<grid, block, 0, stream>>>(
        poses_3d, p2d, vis, nper, Rm, Tm, fm, cm, iw, ih, out);
}

// Round 3
// 40.234 us; speedup vs baseline: 1.0400x; 1.0400x over previous
//
#include <hip/hip_runtime.h>

#define NPERS 64
#define NJOINT 15
#define NDEPTH 128
#define BIGF 100000.0f
#define EPSF 1e-8f
#define NQH 4            // q-split factor
#define QCHUNK (NPERS / NQH)

__global__ __launch_bounds__(512, 8) void pose_match_kernel(
    const float* __restrict__ poses_3d,   // (B,NP,NJ,ND,3)
    const float* __restrict__ p2d,        // (B,NP,NJ,2)
    const float* __restrict__ vis,        // (B,NP,NJ)
    const int*   __restrict__ nper,       // (B,)
    const float* __restrict__ Rm,         // (B,3,3)
    const float* __restrict__ Tm,         // (B,3)
    const float* __restrict__ fm,         // (B,2)
    const float* __restrict__ cm,         // (B,2)
    const float* __restrict__ iw_,        // (B,)
    const float* __restrict__ ih_,        // (B,)
    float* __restrict__ out)              // (B,NP,NJ,ND)
{
    const int b   = blockIdx.x / NPERS;
    const int p   = blockIdx.x % NPERS;
    const int tid = threadIdx.x;
    const int qh  = tid >> 7;     // 0..3: which 16-candidate slice
    const int d   = tid & 127;    // depth bin

    __shared__ float4 sq[NPERS][NJOINT];   // {vis, rx, ry, unused}
    __shared__ float sterm2[NPERS];
    __shared__ float sinv[NPERS];
    __shared__ float bvred[NQH][NDEPTH];
    __shared__ int   bqred[NQH][NDEPTH];

    // ---- stage per-batch candidate data into LDS ----
    for (int i = tid; i < NPERS * NJOINT; i += 512) {
        int q = i / NJOINT, j = i % NJOINT;
        float v  = vis[(b * NPERS + q) * NJOINT + j];
        float rx = p2d[((b * NPERS + q) * NJOINT + j) * 2 + 0];
        float ry = p2d[((b * NPERS + q) * NJOINT + j) * 2 + 1];
        sq[q][j] = make_float4(v, rx, ry, 0.0f);
    }
    __syncthreads();
    if (tid < NPERS) {
        int q = tid;
        float t2 = 0.0f, vs = 0.0f;
        #pragma unroll
        for (int j = 0; j < NJOINT; ++j) {
            float4 v = sq[q][j];
            t2 = fmaf(v.y * v.y + v.z * v.z, v.x, t2);
            vs += v.x;
        }
        sterm2[q] = t2;
        sinv[q]   = 1.0f / (vs + EPSF);
    }
    __syncthreads();

    // ---- camera params (wave-uniform) ----
    const float R00 = Rm[b*9+0], R01 = Rm[b*9+1], R02 = Rm[b*9+2];
    const float R10 = Rm[b*9+3], R11 = Rm[b*9+4], R12 = Rm[b*9+5];
    const float R20 = Rm[b*9+6], R21 = Rm[b*9+7], R22 = Rm[b*9+8];
    const float T0 = Tm[b*3+0], T1 = Tm[b*3+1], T2 = Tm[b*3+2];
    const float fx = fm[b*2+0], fy = fm[b*2+1];
    const float cx = cm[b*2+0], cy = cm[b*2+1];
    const float iwm1 = iw_[b] - 1.0f;
    const float ihm1 = ih_[b] - 1.0f;
    const int   npv  = nper[b];

    // ---- project this thread's 15 joints (duplicated across the 4 qh) ----
    float X[NJOINT], Y[NJOINT], P2[NJOINT];
    #pragma unroll
    for (int j = 0; j < NJOINT; ++j) {
        int base = (((b * NPERS + p) * NJOINT + j) * NDEPTH + d) * 3;
        float a0 = poses_3d[base + 0] - T0;
        float a1 = poses_3d[base + 1] - T1;
        float a2 = poses_3d[base + 2] - T2;
        float xc0 = R00 * a0 + R01 * a1 + R02 * a2;
        float xc1 = R10 * a0 + R11 * a1 + R12 * a2;
        float xc2 = R20 * a0 + R21 * a1 + R22 * a2;
        float xx = fx * xc0 / xc2 + cx;
        float yy = fy * xc1 / xc2 + cy;
        X[j] = xx; Y[j] = yy;
        P2[j] = xx * xx + yy * yy;
    }

    // ---- partial argmin over this thread's 16-candidate slice ----
    // (identical fp arithmetic to the passing round-1 kernel)
    float bestv = 3.0e38f;
    int   bestq = qh * QCHUNK;
    const int q0 = qh * QCHUNK;
    for (int q = q0; q < q0 + QCHUNK; ++q) {
        float s1 = 0.0f, s3 = 0.0f;
        #pragma unroll
        for (int j = 0; j < NJOINT; ++j) {
            float4 v = sq[q][j];
            s1 = fmaf(P2[j], v.x, s1);
            float t = X[j] * v.y;
            t = fmaf(Y[j], v.z, t);
            s3 = fmaf(v.x, t, s3);
        }
        float dist = (s1 + sterm2[q] - 2.0f * s3) * sinv[q];
        dist = (q < npv) ? dist : BIGF;
        if (dist < bestv) { bestv = dist; bestq = q; }
    }
    bvred[qh][d] = bestv;
    bqred[qh][d] = bestq;
    __syncthreads();

    // ---- combine partials (ascending qh, strict <  => np.argmin tie-break)
    //      and run phase 2 on the qh==0 slice ----
    if (qh == 0) {
        #pragma unroll
        for (int k = 1; k < NQH; ++k) {
            float v = bvred[k][d];
            if (v < bestv) { bestv = v; bestq = bqred[k][d]; }
        }
        const int obase = ((b * NPERS + p) * NJOINT) * NDEPTH + d;
        #pragma unroll
        for (int j = 0; j < NJOINT; ++j) {
            float4 v = sq[bestq][j];
            float dx = X[j] - v.y;
            float dy = Y[j] - v.z;
            float md = fmaf(dx, dx, dy * dy);
            float sc = expf(-md * (1.0f / 225.0f));
            float inb = (X[j] >= 0.0f && Y[j] >= 0.0f &&
                         X[j] <= iwm1 && Y[j] <= ihm1) ? 1.0f : 0.0f;
            out[obase + j * NDEPTH] = sc * inb * v.x;
        }
    }
}

extern "C" void kernel_launch(void* const* d_in, const int* in_sizes, int n_in,
                              void* d_out, int out_size, void* d_ws, size_t ws_size,
                              hipStream_t stream) {
    const float* poses_3d = (const float*)d_in[0];
    const float* p2d      = (const float*)d_in[1];
    const float* vis      = (const float*)d_in[2];
    const int*   nper     = (const int*)d_in[3];
    const float* Rm       = (const float*)d_in[4];
    const float* Tm       = (const float*)d_in[5];
    const float* fm       = (const float*)d_in[6];
    const float* cm       = (const float*)d_in[7];
    const float* iw       = (const float*)d_in[8];
    const float* ih       = (const float*)d_in[9];
    float* out = (float*)d_out;

    const int B = in_sizes[3];  // num_persons_ref has B elements
    dim3 grid(B * NPERS);
    dim3 block(512);
    pose_match_kernel<<<grid, block, 0, stream>>>(
        poses_3d, p2d, vis, nper, Rm, Tm, fm, cm, iw, ih, out);
}